// Round 5
// baseline (502.628 us; speedup 1.0000x reference)
//
#include <hip/hip_runtime.h>

typedef __attribute__((ext_vector_type(8))) short short8;
typedef __attribute__((ext_vector_type(4))) float f32x4;

constexpr int TT = 2048, CC = 2048, HQ = 16, GG = 4, DD = 128, IC = 8192;

__device__ __forceinline__ ushort f2b(float f) {
  union { float f; unsigned u; } v; v.f = f;
  unsigned r = v.u + 0x7fffu + ((v.u >> 16) & 1u);
  return (ushort)(r >> 16);
}

__device__ __forceinline__ void gload16(const void* g, void* l) {
  __builtin_amdgcn_global_load_lds(
      (const __attribute__((address_space(1))) void*)g,
      (__attribute__((address_space(3))) void*)l, 16, 0, 0);
}

#define BAR()    __builtin_amdgcn_s_barrier()
#define WAITLG() asm volatile("s_waitcnt lgkmcnt(0)" ::: "memory")
#define SCHED0() __builtin_amdgcn_sched_barrier(0)
#define PRIO1()  __builtin_amdgcn_s_setprio(1)
#define PRIO0()  __builtin_amdgcn_s_setprio(0)

// ============ 256x256 8-phase GEMM (m201 template): C = A[M,K] @ B[N,K]^T, bf16 ============
// EPI 1: Cb = hv(acc) bf16 ; EPI 3: f32 partial plane per blockIdx.z
// 8 waves (2M x 4N), per-wave 128x64, BK=64, 128KB LDS double-buffered.
// Per K-tile, 4 phases; each phase: {in-phase ds_reads (12/4/8/0) | stage 1 half-tile}
//   -> barrier -> lgkmcnt(0) -> sched_barrier -> setprio(1) 16 MFMA setprio(0) -> barrier.
// Counted vmcnt(6) once per tile (3 half-tiles = 6 loads stay in flight across barriers).
// Stage targets always a region whose reads drained >=1 barrier earlier:
//   ph0 -> (t+1,Bh1)[nbuf], ph1 -> (t+2,Ah0)[buf], ph2 -> (t+2,Bh0)[buf], ph3 -> (t+2,Ah1)[buf].
template<int EPI>
__global__ __launch_bounds__(512, 2)
void gemm8p(const ushort* __restrict__ A, const ushort* __restrict__ B,
            float* __restrict__ Cf, ushort* __restrict__ Cb,
            const float* __restrict__ alpha, const float* __restrict__ beta,
            int M, int N, int K, int kc)
{
  __shared__ alignas(16) char lds[131072];
  const int tid = threadIdx.x;
  const int l = tid & 63, w = tid >> 6;
  const int fl = l & 15, fh = l >> 4;
  const int wrm = w >> 2, wcn = w & 3;
  const int m0 = blockIdx.y * 256, n0 = blockIdx.x * 256;
  const int kBeg = blockIdx.z * kc;
  const int kEnd = (kBeg + kc < K) ? kBeg + kc : K;
  const int nt = (kEnd - kBeg) >> 6;

  f32x4 acc[8][4] = {};

  // staging: pre-swizzled global source, linear LDS dest (both-sides rule)
  const int srow = tid >> 3;
  const int scol = ((tid & 7) ^ (srow & 7)) * 8;
  const ushort* Ag = A + (size_t)(m0 + srow) * K + kBeg + scol;
  const ushort* Bg = B + (size_t)(n0 + srow) * K + kBeg + scol;

  // half index h: 0,1 = A halves; 2,3 = B halves
  auto stage_half = [&](int tile, int h) {
    const ushort* base = (h < 2) ? Ag : Bg;
    const int half = h & 1;
    const ushort* g = base + (size_t)(half * 128) * K + tile * 64;
    char* d = lds + (tile & 1) * 65536 + ((h < 2) ? 0 : 32768) + half * 16384 + tid * 16;
    gload16(g, d);
    gload16(g + (size_t)64 * K, d + 8192);
  };

  auto readA = [&](short8 (&dst)[4][2], int buf, int mofs) {
#pragma unroll
    for (int mf = 0; mf < 4; ++mf)
#pragma unroll
      for (int ks = 0; ks < 2; ++ks) {
        int row = wrm * 128 + (mofs + mf) * 16 + fl;
        dst[mf][ks] = *(const short8*)(lds + buf * 65536 + row * 128 +
                                       (((ks * 4 + fh) ^ (row & 7)) * 16));
      }
  };
  auto readB = [&](short8 (&dst)[2][2], int buf, int nofs) {
#pragma unroll
    for (int nf = 0; nf < 2; ++nf)
#pragma unroll
      for (int ks = 0; ks < 2; ++ks) {
        int row = wcn * 64 + (nofs + nf) * 16 + fl;
        dst[nf][ks] = *(const short8*)(lds + buf * 65536 + 32768 + row * 128 +
                                       (((ks * 4 + fh) ^ (row & 7)) * 16));
      }
  };
  auto mmQ = [&](short8 (&a)[4][2], short8 (&b)[2][2], int mo, int no) {
    PRIO1();
#pragma unroll
    for (int mf = 0; mf < 4; ++mf)
#pragma unroll
      for (int nf = 0; nf < 2; ++nf)
#pragma unroll
        for (int ks = 0; ks < 2; ++ks)
          acc[mo + mf][no + nf] = __builtin_amdgcn_mfma_f32_16x16x32_bf16(
              a[mf][ks], b[nf][ks], acc[mo + mf][no + nf], 0, 0, 0);
    PRIO0();
  };

  // prologue: tile0 fully + tile1 h0,h1,h2; wait tile0 (tile1's 6 loads in flight)
  stage_half(0, 0); stage_half(0, 1); stage_half(0, 2); stage_half(0, 3);
  if (nt > 1) {
    stage_half(1, 0); stage_half(1, 1); stage_half(1, 2);
    asm volatile("s_waitcnt vmcnt(6)" ::: "memory");
  } else {
    asm volatile("s_waitcnt vmcnt(0)" ::: "memory");
  }
  BAR();

  for (int t = 0; t < nt; ++t) {
    const int buf = t & 1;
    short8 A0[4][2], A1[4][2], B0[2][2], B1[2][2];

    // ph0: read A0(8)+B0(4); stage (t+1,Bh1); bar; lgkm0; MFMA Q00
    readA(A0, buf, 0);
    readB(B0, buf, 0);
    if (t + 1 < nt) stage_half(t + 1, 3);
    BAR(); WAITLG(); SCHED0();
    mmQ(A0, B0, 0, 0);
    BAR();

    // ph1: read B1(4); stage (t+2,Ah0); bar; lgkm0; MFMA Q01
    readB(B1, buf, 2);
    if (t + 2 < nt) stage_half(t + 2, 0);
    BAR(); WAITLG(); SCHED0();
    mmQ(A0, B1, 0, 2);
    BAR();

    // ph2: read A1(8); stage (t+2,Bh0); bar; lgkm0; MFMA Q10
    readA(A1, buf, 4);
    if (t + 2 < nt) stage_half(t + 2, 2);
    BAR(); WAITLG(); SCHED0();
    mmQ(A1, B0, 4, 0);
    BAR();

    // ph3: stage (t+2,Ah1); counted vmcnt; bar; MFMA Q11 (no reads)
    if (t + 2 < nt) {
      stage_half(t + 2, 1);
      asm volatile("s_waitcnt vmcnt(6)" ::: "memory");
    } else {
      asm volatile("s_waitcnt vmcnt(0)" ::: "memory");
    }
    BAR();
    mmQ(A1, B1, 4, 2);
    BAR();
  }

  const int orow0 = m0 + wrm * 128 + fh * 4;
  const int ocol0 = n0 + wcn * 64 + fl;
  float* Cpart = (EPI == 3) ? (Cf + (size_t)blockIdx.z * M * N) : Cf;
#pragma unroll
  for (int mf = 0; mf < 8; ++mf) {
#pragma unroll
    for (int nf = 0; nf < 4; ++nf) {
      const int c = ocol0 + nf * 16;
#pragma unroll
      for (int j = 0; j < 4; ++j) {
        const int r = orow0 + mf * 16 + j;
        const size_t o = (size_t)r * N + c;
        float v = acc[mf][nf][j];
        if constexpr (EPI == 1) {
          Cb[o] = (v - beta[c] > 0.f) ? f2b(alpha[c]) : (ushort)0;
        } else {
          Cpart[o] = v;
        }
      }
    }
  }
}

// ---------------- split-K reduce (per-plane pointers; p-planes may alias outf) ----------------
// MODE 1: outf = resid+sum, outb = hv(outf) ; MODE 2: outf = resid+sum
template<int NS, int MODE>
__global__ void reduce_kernel(const float* p0, const float* p1, const float* p2, const float* p3,
                              const float* resid, float* outf, ushort* outb,
                              const float* alpha, const float* beta, int n4, int cols)
{
  const float* ps[4] = {p0, p1, p2, p3};
  for (int i = blockIdx.x * blockDim.x + threadIdx.x; i < n4; i += gridDim.x * blockDim.x) {
    float4 s = ((const float4*)ps[0])[i];
#pragma unroll
    for (int z = 1; z < NS; ++z) {
      float4 p = ((const float4*)ps[z])[i];
      s.x += p.x; s.y += p.y; s.z += p.z; s.w += p.w;
    }
    float4 rr = ((const float4*)resid)[i];
    s.x += rr.x; s.y += rr.y; s.z += rr.z; s.w += rr.w;
    ((float4*)outf)[i] = s;
    if constexpr (MODE == 1) {
      int c = (i * 4) & (cols - 1);
      ushort4 r;
      r.x = (s.x - beta[c] > 0.f) ? f2b(alpha[c]) : (ushort)0;
      r.y = (s.y - beta[c + 1] > 0.f) ? f2b(alpha[c + 1]) : (ushort)0;
      r.z = (s.z - beta[c + 2] > 0.f) ? f2b(alpha[c + 2]) : (ushort)0;
      r.w = (s.w - beta[c + 3] > 0.f) ? f2b(alpha[c + 3]) : (ushort)0;
      ((ushort4*)outb)[i] = r;
    }
  }
}

// ---------------- fused causal relu-attention ----------------
__global__ __launch_bounds__(256)
void attn_kernel(const ushort* __restrict__ qb, const ushort* __restrict__ kb,
                 const ushort* __restrict__ vt, ushort* __restrict__ hy,
                 const float* __restrict__ oalpha, const float* __restrict__ obeta)
{
  __shared__ alignas(16) ushort Qs[64 * 128];
  __shared__ alignas(16) ushort Ks[64 * 128];
  __shared__ alignas(16) ushort Vs[128 * 64];
  __shared__ alignas(16) ushort Ps[64 * 64];
  const int qi = gridDim.x - 1 - blockIdx.x;   // heavy q-tiles dispatch first
  const int h = blockIdx.y;
  const int g = h >> 2;
  const int q0 = qi * 64;
  const int tid = threadIdx.x;
  const int w = tid >> 6, l = tid & 63;
  const int fl = l & 15, fh = l >> 4;

#pragma unroll
  for (int i = 0; i < 4; ++i) {
    int row = w * 16 + i * 4 + (l >> 4);
    int c16 = (l & 15) ^ (row & 7);
    gload16(qb + (size_t)h * TT * DD + (size_t)(q0 + row) * DD + c16 * 8,
            (char*)Qs + (w << 12) + (i << 10) + (l << 4));
  }

  f32x4 oacc[8] = {};

  for (int s0 = 0; s0 <= q0; s0 += 64) {
#pragma unroll
    for (int i = 0; i < 4; ++i) {
      int row = w * 16 + i * 4 + (l >> 4);
      int c16 = (l & 15) ^ (row & 7);
      gload16(kb + (size_t)g * TT * DD + (size_t)(s0 + row) * DD + c16 * 8,
              (char*)Ks + (w << 12) + (i << 10) + (l << 4));
    }
#pragma unroll
    for (int i = 0; i < 4; ++i) {
      int d = w * 32 + i * 8 + (l >> 3);
      int c16 = (l & 7) ^ (d & 7);
      gload16(vt + (size_t)g * DD * TT + (size_t)d * TT + s0 + c16 * 8,
              (char*)Vs + (w << 12) + (i << 10) + (l << 4));
    }
    __syncthreads();

    f32x4 sacc[4] = {};
    const int qrow = w * 16 + fl;
#pragma unroll
    for (int ks = 0; ks < 4; ++ks) {
      int slotA = (ks * 4 + fh) ^ (qrow & 7);
      short8 a = *(const short8*)((char*)Qs + qrow * 256 + slotA * 16);
#pragma unroll
      for (int n = 0; n < 4; ++n) {
        int krow = n * 16 + fl;
        int slotB = (ks * 4 + fh) ^ (krow & 7);
        short8 b = *(const short8*)((char*)Ks + krow * 256 + slotB * 16);
        sacc[n] = __builtin_amdgcn_mfma_f32_16x16x32_bf16(a, b, sacc[n], 0, 0, 0);
      }
    }

#pragma unroll
    for (int n = 0; n < 4; ++n) {
      const int scol = s0 + n * 16 + fl;
#pragma unroll
      for (int j = 0; j < 4; ++j) {
        const int pr = w * 16 + fh * 4 + j;
        const int qr = q0 + pr;
        float v = sacc[n][j] * 0.0078125f;
        ushort pv = (scol <= qr && v > 0.f) ? f2b(v) : (ushort)0;
        int slot = ((n * 2) + (fl >> 3)) ^ (pr & 7);
        ((ushort*)((char*)Ps + pr * 128 + slot * 16))[fl & 7] = pv;
      }
    }

    const int prow = w * 16 + fl;
#pragma unroll
    for (int ks = 0; ks < 2; ++ks) {
      int slotA = (ks * 4 + fh) ^ (prow & 7);
      short8 pa = *(const short8*)((char*)Ps + prow * 128 + slotA * 16);
#pragma unroll
      for (int n = 0; n < 8; ++n) {
        int vrow = n * 16 + fl;
        int slotB = (ks * 4 + fh) ^ (vrow & 7);
        short8 vb = *(const short8*)((char*)Vs + vrow * 128 + slotB * 16);
        oacc[n] = __builtin_amdgcn_mfma_f32_16x16x32_bf16(pa, vb, oacc[n], 0, 0, 0);
      }
    }
    __syncthreads();
  }

#pragma unroll
  for (int n = 0; n < 8; ++n) {
    const int c = h * DD + n * 16 + fl;
    const float al = oalpha[c], be = obeta[c];
#pragma unroll
    for (int j = 0; j < 4; ++j) {
      const int tq = q0 + w * 16 + fh * 4 + j;
      float v = oacc[n][j];
      hy[(size_t)tq * CC + c] = (v - be > 0.f) ? f2b(al) : (ushort)0;
    }
  }
}

// ---------- rope + hv on q/k, transpose+cast v ; fused split-K-2 sum ----------
__global__ __launch_bounds__(256)
void rope_hv_kernel(const float* __restrict__ qp0, const float* __restrict__ qp1,
                    const float* __restrict__ cs, const float* __restrict__ sn,
                    const float* __restrict__ qalpha, const float* __restrict__ qbeta,
                    const float* __restrict__ kalpha, const float* __restrict__ kbeta,
                    ushort* __restrict__ qb, ushort* __restrict__ kb,
                    ushort* __restrict__ vt)
{
  __shared__ ushort Vsh[64][129];
  const int t0 = blockIdx.x * 64, g = blockIdx.y;
  const int tid = threadIdx.x;
#pragma unroll
  for (int hh = 0; hh < 5; ++hh) {
    const float* alpha = (hh < 4) ? qalpha : kalpha;
    const float* beta = (hh < 4) ? qbeta : kbeta;
    const int hoff = (hh < 4) ? hh * 128 : 512;
    for (int it = 0; it < 16; ++it) {
      int idx = it * 256 + tid;
      int tr = idx >> 6, dd = idx & 63;
      size_t base = (size_t)(t0 + tr) * 3072 + g * 768 + hoff;
      float x1 = qp0[base + dd] + qp1[base + dd];
      float x2 = qp0[base + 64 + dd] + qp1[base + 64 + dd];
      float c = cs[(size_t)(t0 + tr) * 64 + dd];
      float s = sn[(size_t)(t0 + tr) * 64 + dd];
      float o1 = x1 * c - x2 * s, o2 = x1 * s + x2 * c;
      ushort b1 = (o1 - beta[dd] > 0.f) ? f2b(alpha[dd]) : (ushort)0;
      ushort b2 = (o2 - beta[64 + dd] > 0.f) ? f2b(alpha[64 + dd]) : (ushort)0;
      if (hh < 4) {
        size_t o = ((size_t)(g * 4 + hh) * TT + t0 + tr) * DD;
        qb[o + dd] = b1;
        qb[o + 64 + dd] = b2;
      } else {
        size_t o = ((size_t)g * TT + t0 + tr) * DD;
        kb[o + dd] = b1;
        kb[o + 64 + dd] = b2;
      }
    }
  }
  for (int it = 0; it < 32; ++it) {
    int idx = it * 256 + tid;
    int tr = idx >> 7, d = idx & 127;
    size_t src = (size_t)(t0 + tr) * 3072 + g * 768 + 640 + d;
    Vsh[tr][d] = f2b(qp0[src] + qp1[src]);
  }
  __syncthreads();
  for (int it = 0; it < 32; ++it) {
    int idx = it * 256 + tid;
    int d = idx >> 6, tl = idx & 63;
    vt[((size_t)g * DD + d) * TT + t0 + tl] = Vsh[tl][d];
  }
}

// ---------------- elementwise ----------------
__global__ void hv_cast_kernel(const float* __restrict__ x, const float* __restrict__ alpha,
                               const float* __restrict__ beta, ushort* __restrict__ out,
                               int n4, int cols) {
  for (int i = blockIdx.x * blockDim.x + threadIdx.x; i < n4; i += gridDim.x * blockDim.x) {
    float4 v = ((const float4*)x)[i];
    int c = (i * 4) & (cols - 1);
    ushort4 r;
    r.x = (v.x - beta[c] > 0.f) ? f2b(alpha[c]) : (ushort)0;
    r.y = (v.y - beta[c + 1] > 0.f) ? f2b(alpha[c + 1]) : (ushort)0;
    r.z = (v.z - beta[c + 2] > 0.f) ? f2b(alpha[c + 2]) : (ushort)0;
    r.w = (v.w - beta[c + 3] > 0.f) ? f2b(alpha[c + 3]) : (ushort)0;
    ((ushort4*)out)[i] = r;
  }
}

__global__ void cast_kernel(const float* __restrict__ x, ushort* __restrict__ out, int n4) {
  for (int i = blockIdx.x * blockDim.x + threadIdx.x; i < n4; i += gridDim.x * blockDim.x) {
    float4 v = ((const float4*)x)[i];
    ushort4 r;
    r.x = f2b(v.x); r.y = f2b(v.y); r.z = f2b(v.z); r.w = f2b(v.w);
    ((ushort4*)out)[i] = r;
  }
}

__global__ void norm_cast_kernel(const float* __restrict__ W, const float* __restrict__ mu,
                                 const float* __restrict__ inv, ushort* __restrict__ out,
                                 int n4, int cols) {
  for (int i = blockIdx.x * blockDim.x + threadIdx.x; i < n4; i += gridDim.x * blockDim.x) {
    float4 v = ((const float4*)W)[i];
    int c = (i * 4) & (cols - 1);
    ushort4 r;
    r.x = f2b((v.x - mu[c]) * inv[c]);
    r.y = f2b((v.y - mu[c + 1]) * inv[c + 1]);
    r.z = f2b((v.z - mu[c + 2]) * inv[c + 2]);
    r.w = f2b((v.w - mu[c + 3]) * inv[c + 3]);
    ((ushort4*)out)[i] = r;
  }
}

// ---------------- column stats ----------------
__global__ void stats1_kernel(const float* __restrict__ W, float* __restrict__ ps,
                              float* __restrict__ ps2, int cols) {
  int j = blockIdx.x * 256 + threadIdx.x;
  int chunk = blockIdx.y;
  const float* p = W + (size_t)chunk * 256 * cols + j;
  float s = 0.f, s2 = 0.f;
  for (int i = 0; i < 256; ++i) { float v = p[(size_t)i * cols]; s += v; s2 += v * v; }
  ps[chunk * cols + j] = s;
  ps2[chunk * cols + j] = s2;
}

__global__ void stats2_kernel(const float* __restrict__ ps, const float* __restrict__ ps2,
                              float* __restrict__ mu, float* __restrict__ inv,
                              const float* __restrict__ scale, int cols) {
  int j = blockIdx.x * 256 + threadIdx.x;
  float s = 0.f, s2 = 0.f;
  for (int c = 0; c < 8; ++c) { s += ps[c * cols + j]; s2 += ps2[c * cols + j]; }
  float m = s * (1.f / 2048.f);
  float var = s2 - s * m;
  float nn = sqrtf(fmaxf(var, 0.f));
  nn = fmaxf(nn, 1e-12f);
  mu[j] = m;
  inv[j] = scale[0] / nn;
}

extern "C" void kernel_launch(void* const* d_in, const int* in_sizes, int n_in,
                              void* d_out, int out_size, void* d_ws, size_t ws_size,
                              hipStream_t stream) {
  const float* x          = (const float*)d_in[0];
  const float* cosT       = (const float*)d_in[1];
  const float* sinT       = (const float*)d_in[2];
  const float* attn_w     = (const float*)d_in[3];
  const float* proj_w     = (const float*)d_in[4];
  const float* proj_scale = (const float*)d_in[5];
  const float* fc_w       = (const float*)d_in[6];
  const float* mlp_proj_w = (const float*)d_in[7];
  const float* mlp_scale  = (const float*)d_in[8];
  const float* in_alpha   = (const float*)d_in[9];
  const float* in_beta    = (const float*)d_in[10];
  const float* q_alpha    = (const float*)d_in[11];
  const float* q_beta     = (const float*)d_in[12];
  const float* k_alpha    = (const float*)d_in[13];
  const float* k_beta     = (const float*)d_in[14];
  const float* out_alpha  = (const float*)d_in[15];
  const float* out_beta   = (const float*)d_in[16];
  const float* act1_alpha = (const float*)d_in[17];
  const float* act1_beta  = (const float*)d_in[18];
  const float* act2_alpha = (const float*)d_in[19];
  const float* act2_beta  = (const float*)d_in[20];

  char* cur = (char*)d_ws;
  auto alloc = [&](size_t b) { void* p = cur; cur += (b + 255) & ~(size_t)255; return p; };

  // --- early-dead cluster (dead after attn): contiguous 58.73MB ---
  ushort* attn_wb = (ushort*)alloc((size_t)3072 * 2048 * 2);
  ushort* h_in    = (ushort*)alloc((size_t)2048 * 2048 * 2);
  float*  qkv     = (float*)alloc((size_t)2048 * 3072 * 4);   // scratch (part of cluster)
  ushort* qbuf    = (ushort*)alloc((size_t)HQ * TT * DD * 2);
  ushort* kbuf    = (ushort*)alloc((size_t)GG * TT * DD * 2);
  ushort* vtbuf   = (ushort*)alloc((size_t)GG * DD * TT * 2);
  // --- mid-dead ---
  ushort* projn   = (ushort*)alloc((size_t)2048 * 2048 * 2);
  ushort* fc_wb   = (ushort*)alloc((size_t)8192 * 2048 * 2);
  // --- live-late ---
  ushort* mlpn    = (ushort*)alloc((size_t)2048 * 8192 * 2);
  ushort* h_y     = (ushort*)alloc((size_t)2048 * 2048 * 2);
  float*  x2      = (float*)alloc((size_t)2048 * 2048 * 4);
  ushort* h2      = (ushort*)alloc((size_t)2048 * 2048 * 2);
  ushort* h3      = (ushort*)alloc((size_t)2048 * 8192 * 2);
  float* pp_s  = (float*)alloc(8 * 2048 * 4);
  float* pp_s2 = (float*)alloc(8 * 2048 * 4);
  float* mp_s  = (float*)alloc(8 * 8192 * 4);
  float* mp_s2 = (float*)alloc(8 * 8192 * 4);
  float* p_mu  = (float*)alloc(2048 * 4);
  float* p_inv = (float*)alloc(2048 * 4);
  float* m_mu  = (float*)alloc(8192 * 4);
  float* m_inv = (float*)alloc(8192 * 4);
  (void)qkv;

  const size_t PLANE_QKV = (size_t)2048 * 3072;
  const size_t PLANE     = (size_t)2048 * 2048;

  // split-K part planes alias dead regions:
  float* qkv_parts  = (float*)x2;       // 2 planes over [x2,h2,h3]=58.7MB (written later)
  float* cluster    = (float*)attn_wb;  // 58.73MB early-dead
  // proj: planes 0-2 in cluster, plane 3 in x2 region (reduce reads p3[i] before writing x2[i])
  float* proj_p3    = (float*)x2;
  // mlp: 4 planes over [cluster,projn,fc_wb] = 100.7MB contiguous
  float* mlp_parts  = (float*)attn_wb;

  // weight prep
  stats1_kernel<<<dim3(8, 8), 256, 0, stream>>>(proj_w, pp_s, pp_s2, 2048);
  stats1_kernel<<<dim3(32, 8), 256, 0, stream>>>(mlp_proj_w, mp_s, mp_s2, 8192);
  stats2_kernel<<<8, 256, 0, stream>>>(pp_s, pp_s2, p_mu, p_inv, proj_scale, 2048);
  stats2_kernel<<<32, 256, 0, stream>>>(mp_s, mp_s2, m_mu, m_inv, mlp_scale, 8192);
  norm_cast_kernel<<<2048, 256, 0, stream>>>(proj_w, p_mu, p_inv, projn, 2048 * 2048 / 4, 2048);
  norm_cast_kernel<<<2048, 256, 0, stream>>>(mlp_proj_w, m_mu, m_inv, mlpn, 2048 * 8192 / 4, 8192);
  cast_kernel<<<2048, 256, 0, stream>>>(attn_w, attn_wb, 3072 * 2048 / 4);
  cast_kernel<<<2048, 256, 0, stream>>>(fc_w, fc_wb, 8192 * 2048 / 4);

  // h = hv(x)
  hv_cast_kernel<<<2048, 256, 0, stream>>>(x, in_alpha, in_beta, h_in, 2048 * 2048 / 4, 2048);

  // qkv = h @ attn_w^T   (split-K x2; sum fused into rope)
  gemm8p<3><<<dim3(3072 / 256, 2048 / 256, 2), 512, 0, stream>>>(
      h_in, attn_wb, qkv_parts, nullptr, nullptr, nullptr, 2048, 3072, 2048, 1024);

  // rope + hv -> q,k ; transpose v  (reads & sums the two qkv part planes)
  rope_hv_kernel<<<dim3(TT / 64, GG), 256, 0, stream>>>(
      qkv_parts, qkv_parts + PLANE_QKV, cosT, sinT,
      q_alpha, q_beta, k_alpha, k_beta, qbuf, kbuf, vtbuf);

  // fused causal relu attention, hv epilogue -> h_y
  attn_kernel<<<dim3(TT / 64, HQ), 256, 0, stream>>>(qbuf, kbuf, vtbuf, h_y, out_alpha, out_beta);

  // x2 = x + h_y @ projn^T (split-K x4, kc=512, 256 blocks), fused h2 = hv(x2)
  // planes 0-2 -> cluster, plane 3 -> x2 region (blockIdx.z==3 writes proj_p3)
  {
    // plane pointers for gemm: Cpart = Cf + z*M*N. Use cluster base; z==3 plane would be
    // cluster+3*PLANE which exceeds cluster — so run z=0..2 on cluster and z==3 separately.
    gemm8p<3><<<dim3(8, 8, 3), 512, 0, stream>>>(
        h_y, projn, cluster, nullptr, nullptr, nullptr, 2048, 2048, 2048, 512);
    // 4th slice (kBeg = 3*512): single-plane partial into x2 region
    const ushort* h_y4 = h_y;  // same A
    gemm8p<3><<<dim3(8, 8, 1), 512, 0, stream>>>(
        h_y4 + 0, projn + 0, proj_p3 - (size_t)0, nullptr, nullptr, nullptr,
        2048, 2048, 2048, 512);  // placeholder; replaced below
  }
  // NOTE: the call above with blockIdx.z==0 computes kBeg=0, not the 4th slice.
  // Correct approach: shift A/B pointers by 3*512 along K and set kc=512, K=512.
  // (Overwrite the erroneous partial with the correct one — same buffer, deterministic.)
  gemm8p<3><<<dim3(8, 8, 1), 512, 0, stream>>>(
      h_y + 3 * 512, projn + 3 * 512, proj_p3, nullptr, nullptr, nullptr,
      2048, 2048, 2048 /*row stride K*/, 0 /*unused*/ + 512);
  reduce_kernel<4, 1><<<2048, 256, 0, stream>>>(
      cluster, cluster + PLANE, cluster + 2 * PLANE, proj_p3,
      x, x2, h2, act1_alpha, act1_beta, 2048 * 2048 / 4, 2048);

  // h3 = hv(h2 @ fc_w^T)   (256 blocks, 1/CU, no split)
  gemm8p<1><<<dim3(8192 / 256, 2048 / 256, 1), 512, 0, stream>>>(
      h2, fc_wb, nullptr, h3, act2_alpha, act2_beta, 2048, 8192, 2048, 2048);

  // out = x2 + h3 @ mlpn^T (split-K x4, kc=2048, 256 blocks)
  gemm8p<3><<<dim3(8, 8, 4), 512, 0, stream>>>(
      h3, mlpn, mlp_parts, nullptr, nullptr, nullptr, 2048, 2048, 8192, 2048);
  reduce_kernel<4, 2><<<2048, 256, 0, stream>>>(
      mlp_parts, mlp_parts + PLANE, mlp_parts + 2 * PLANE, mlp_parts + 3 * PLANE,
      x2, (float*)d_out, nullptr, nullptr, nullptr, 2048 * 2048 / 4, 1);
}

// Round 6
// 448.054 us; speedup vs baseline: 1.1218x; 1.1218x over previous
//
#include <hip/hip_runtime.h>

typedef __attribute__((ext_vector_type(8))) short short8;
typedef __attribute__((ext_vector_type(4))) float f32x4;

constexpr int TT = 2048, CC = 2048, HQ = 16, GG = 4, DD = 128, IC = 8192;

__device__ __forceinline__ ushort f2b(float f) {
  union { float f; unsigned u; } v; v.f = f;
  unsigned r = v.u + 0x7fffu + ((v.u >> 16) & 1u);
  return (ushort)(r >> 16);
}

__device__ __forceinline__ void gload16(const void* g, void* l) {
  __builtin_amdgcn_global_load_lds(
      (const __attribute__((address_space(1))) void*)g,
      (__attribute__((address_space(3))) void*)l, 16, 0, 0);
}

#define BAR()    __builtin_amdgcn_s_barrier()
#define PRIO1()  __builtin_amdgcn_s_setprio(1)
#define PRIO0()  __builtin_amdgcn_s_setprio(0)

// ============ 256x256 GEMM, relaxed 1-barrier pipeline: C = A[M,K] @ B[N,K]^T (bf16) ============
// EPI 1: Cb = hv(acc) bf16 ; EPI 3: f32 partial plane per blockIdx.z
// 8 waves (2M x 4N), per-wave 128x64, BK=64, 128KB LDS double-buffered (1 block/CU).
// Per phase: {ds_reads | stage} -> s_barrier -> MFMA quadrant. NO lgkmcnt(0), NO
// sched_barrier: the compiler emits counted lgkm waits, so phase p+1's read drain
// overlaps phase p's MFMA (intra-block pipelining; only 1 block fits so cross-block
// overlap is impossible). Stage safety invariant (derived, 1-bar/phase): a stage
// issued in window p may target only regions whose last ds_read was at phase <= p-2.
//   A[buf] reads: A0-rows(ph0) = {0-63,128-191}, A1-rows(ph2) = {64-127,192-255}
//   B[buf] reads: B0-rows(ph0) (bit5=0), B1-rows(ph1) (bit5=1) -> B fully read after ph1.
// Mapping: ph0 -> Ah0(t+1)[nb] (last read (t-1,ph2) = p-2 OK), ph1 -> Ah1(t+1)[nb] (OK),
//          ph3 -> Bh0(t+2)+Bh1(t+2)[buf] (last read (t,ph1) = p-2 OK).
// One vmcnt(4) per tile before BAR(ph3): drains all of tile t+1 (allows the 4 B(t+2)
// loads just issued to fly). Last 2 tiles: vmcnt(0). (This also fixes R4/R5's latent
// stage-vs-read race: Ah0(t+2)@ph1 overlapped ph2's A1 reads of rows 64-127.)
template<int EPI>
__global__ __launch_bounds__(512, 2)
void gemm8p(const ushort* __restrict__ A, const ushort* __restrict__ B,
            float* __restrict__ Cf, ushort* __restrict__ Cb,
            const float* __restrict__ alpha, const float* __restrict__ beta,
            int M, int N, int K, int kc)
{
  __shared__ alignas(16) char lds[131072];
  const int tid = threadIdx.x;
  const int l = tid & 63, w = tid >> 6;
  const int fl = l & 15, fh = l >> 4;
  const int wrm = w >> 2, wcn = w & 3;
  const int m0 = blockIdx.y * 256, n0 = blockIdx.x * 256;
  const int kBeg = blockIdx.z * kc;
  const int kEnd = (kBeg + kc < K) ? kBeg + kc : K;
  const int nt = (kEnd - kBeg) >> 6;

  f32x4 acc[8][4] = {};

  // staging: pre-swizzled global source, linear LDS dest (both-sides rule)
  const int srow = tid >> 3;
  const int scol = ((tid & 7) ^ (srow & 7)) * 8;
  const ushort* Ag = A + (size_t)(m0 + srow) * K + kBeg + scol;
  const ushort* Bg = B + (size_t)(n0 + srow) * K + kBeg + scol;

  // h: 0 = Ah0 (rows 0-127), 1 = Ah1 (128-255), 2 = Bh0, 3 = Bh1
  auto stage_half = [&](int tile, int h) {
    const ushort* base = (h < 2) ? Ag : Bg;
    const int half = h & 1;
    const ushort* g = base + (size_t)(half * 128) * K + tile * 64;
    char* d = lds + (tile & 1) * 65536 + ((h < 2) ? 0 : 32768) + half * 16384 + tid * 16;
    gload16(g, d);
    gload16(g + (size_t)64 * K, d + 8192);
  };

  auto readA = [&](short8 (&dst)[4][2], int buf, int mofs) {
#pragma unroll
    for (int mf = 0; mf < 4; ++mf)
#pragma unroll
      for (int ks = 0; ks < 2; ++ks) {
        int row = wrm * 128 + (mofs + mf) * 16 + fl;
        dst[mf][ks] = *(const short8*)(lds + buf * 65536 + row * 128 +
                                       (((ks * 4 + fh) ^ (row & 7)) * 16));
      }
  };
  auto readB = [&](short8 (&dst)[2][2], int buf, int nofs) {
#pragma unroll
    for (int nf = 0; nf < 2; ++nf)
#pragma unroll
      for (int ks = 0; ks < 2; ++ks) {
        int row = wcn * 64 + (nofs + nf) * 16 + fl;
        dst[nf][ks] = *(const short8*)(lds + buf * 65536 + 32768 + row * 128 +
                                       (((ks * 4 + fh) ^ (row & 7)) * 16));
      }
  };
  auto mmQ = [&](short8 (&a)[4][2], short8 (&b)[2][2], int mo, int no) {
    PRIO1();
#pragma unroll
    for (int mf = 0; mf < 4; ++mf)
#pragma unroll
      for (int nf = 0; nf < 2; ++nf)
#pragma unroll
        for (int ks = 0; ks < 2; ++ks)
          acc[mo + mf][no + nf] = __builtin_amdgcn_mfma_f32_16x16x32_bf16(
              a[mf][ks], b[nf][ks], acc[mo + mf][no + nf], 0, 0, 0);
    PRIO0();
  };

  // prologue: tile0 fully (8 loads) + tile1 B halves (4 loads, the "t-1 ph3" stages)
  stage_half(0, 0); stage_half(0, 1); stage_half(0, 2); stage_half(0, 3);
  if (nt > 1) {
    stage_half(1, 2); stage_half(1, 3);
    asm volatile("s_waitcnt vmcnt(4)" ::: "memory");
  } else {
    asm volatile("s_waitcnt vmcnt(0)" ::: "memory");
  }
  BAR();

  for (int t = 0; t < nt; ++t) {
    const int buf = t & 1;
    short8 A0[4][2], A1[4][2], B0[2][2], B1[2][2];

    // ph0: reads A0,B0[buf]; stage Ah0(t+1)[nb]; BAR; MFMA Q00
    readA(A0, buf, 0);
    readB(B0, buf, 0);
    if (t + 1 < nt) stage_half(t + 1, 0);
    BAR();
    mmQ(A0, B0, 0, 0);

    // ph1: reads B1[buf]; stage Ah1(t+1)[nb]; BAR; MFMA Q01
    readB(B1, buf, 2);
    if (t + 1 < nt) stage_half(t + 1, 1);
    BAR();
    mmQ(A0, B1, 0, 2);

    // ph2: reads A1[buf]; BAR; MFMA Q10
    readA(A1, buf, 4);
    BAR();
    mmQ(A1, B0, 4, 0);

    // ph3: stage Bh0+Bh1(t+2)[buf]; vmcnt(4) (drains all of tile t+1); BAR; MFMA Q11
    if (t + 2 < nt) { stage_half(t + 2, 2); stage_half(t + 2, 3); }
    if (t <= nt - 3) asm volatile("s_waitcnt vmcnt(4)" ::: "memory");
    else             asm volatile("s_waitcnt vmcnt(0)" ::: "memory");
    BAR();
    mmQ(A1, B1, 4, 2);
  }

  const int orow0 = m0 + wrm * 128 + fh * 4;
  const int ocol0 = n0 + wcn * 64 + fl;
  float* Cpart = (EPI == 3) ? (Cf + (size_t)blockIdx.z * M * N) : Cf;
#pragma unroll
  for (int mf = 0; mf < 8; ++mf) {
#pragma unroll
    for (int nf = 0; nf < 4; ++nf) {
      const int c = ocol0 + nf * 16;
#pragma unroll
      for (int j = 0; j < 4; ++j) {
        const int r = orow0 + mf * 16 + j;
        const size_t o = (size_t)r * N + c;
        float v = acc[mf][nf][j];
        if constexpr (EPI == 1) {
          Cb[o] = (v - beta[c] > 0.f) ? f2b(alpha[c]) : (ushort)0;
        } else {
          Cpart[o] = v;
        }
      }
    }
  }
}

// ---------------- split-K reduce (per-plane pointers) ----------------
// MODE 1: outf = resid+sum, outb = hv(outf) ; MODE 2: outf = resid+sum
template<int NS, int MODE>
__global__ void reduce_kernel(const float* p0, const float* p1, const float* p2, const float* p3,
                              const float* resid, float* outf, ushort* outb,
                              const float* alpha, const float* beta, int n4, int cols)
{
  const float* ps[4] = {p0, p1, p2, p3};
  for (int i = blockIdx.x * blockDim.x + threadIdx.x; i < n4; i += gridDim.x * blockDim.x) {
    float4 s = ((const float4*)ps[0])[i];
#pragma unroll
    for (int z = 1; z < NS; ++z) {
      float4 p = ((const float4*)ps[z])[i];
      s.x += p.x; s.y += p.y; s.z += p.z; s.w += p.w;
    }
    float4 rr = ((const float4*)resid)[i];
    s.x += rr.x; s.y += rr.y; s.z += rr.z; s.w += rr.w;
    ((float4*)outf)[i] = s;
    if constexpr (MODE == 1) {
      int c = (i * 4) & (cols - 1);
      ushort4 r;
      r.x = (s.x - beta[c] > 0.f) ? f2b(alpha[c]) : (ushort)0;
      r.y = (s.y - beta[c + 1] > 0.f) ? f2b(alpha[c + 1]) : (ushort)0;
      r.z = (s.z - beta[c + 2] > 0.f) ? f2b(alpha[c + 2]) : (ushort)0;
      r.w = (s.w - beta[c + 3] > 0.f) ? f2b(alpha[c + 3]) : (ushort)0;
      ((ushort4*)outb)[i] = r;
    }
  }
}

// ---------------- fused causal relu-attention ----------------
__global__ __launch_bounds__(256)
void attn_kernel(const ushort* __restrict__ qb, const ushort* __restrict__ kb,
                 const ushort* __restrict__ vt, ushort* __restrict__ hy,
                 const float* __restrict__ oalpha, const float* __restrict__ obeta)
{
  __shared__ alignas(16) ushort Qs[64 * 128];
  __shared__ alignas(16) ushort Ks[64 * 128];
  __shared__ alignas(16) ushort Vs[128 * 64];
  __shared__ alignas(16) ushort Ps[64 * 64];
  const int qi = gridDim.x - 1 - blockIdx.x;   // heavy q-tiles dispatch first
  const int h = blockIdx.y;
  const int g = h >> 2;
  const int q0 = qi * 64;
  const int tid = threadIdx.x;
  const int w = tid >> 6, l = tid & 63;
  const int fl = l & 15, fh = l >> 4;

#pragma unroll
  for (int i = 0; i < 4; ++i) {
    int row = w * 16 + i * 4 + (l >> 4);
    int c16 = (l & 15) ^ (row & 7);
    gload16(qb + (size_t)h * TT * DD + (size_t)(q0 + row) * DD + c16 * 8,
            (char*)Qs + (w << 12) + (i << 10) + (l << 4));
  }

  f32x4 oacc[8] = {};

  for (int s0 = 0; s0 <= q0; s0 += 64) {
#pragma unroll
    for (int i = 0; i < 4; ++i) {
      int row = w * 16 + i * 4 + (l >> 4);
      int c16 = (l & 15) ^ (row & 7);
      gload16(kb + (size_t)g * TT * DD + (size_t)(s0 + row) * DD + c16 * 8,
              (char*)Ks + (w << 12) + (i << 10) + (l << 4));
    }
#pragma unroll
    for (int i = 0; i < 4; ++i) {
      int d = w * 32 + i * 8 + (l >> 3);
      int c16 = (l & 7) ^ (d & 7);
      gload16(vt + (size_t)g * DD * TT + (size_t)d * TT + s0 + c16 * 8,
              (char*)Vs + (w << 12) + (i << 10) + (l << 4));
    }
    __syncthreads();

    f32x4 sacc[4] = {};
    const int qrow = w * 16 + fl;
#pragma unroll
    for (int ks = 0; ks < 4; ++ks) {
      int slotA = (ks * 4 + fh) ^ (qrow & 7);
      short8 a = *(const short8*)((char*)Qs + qrow * 256 + slotA * 16);
#pragma unroll
      for (int n = 0; n < 4; ++n) {
        int krow = n * 16 + fl;
        int slotB = (ks * 4 + fh) ^ (krow & 7);
        short8 b = *(const short8*)((char*)Ks + krow * 256 + slotB * 16);
        sacc[n] = __builtin_amdgcn_mfma_f32_16x16x32_bf16(a, b, sacc[n], 0, 0, 0);
      }
    }

#pragma unroll
    for (int n = 0; n < 4; ++n) {
      const int scol = s0 + n * 16 + fl;
#pragma unroll
      for (int j = 0; j < 4; ++j) {
        const int pr = w * 16 + fh * 4 + j;
        const int qr = q0 + pr;
        float v = sacc[n][j] * 0.0078125f;
        ushort pv = (scol <= qr && v > 0.f) ? f2b(v) : (ushort)0;
        int slot = ((n * 2) + (fl >> 3)) ^ (pr & 7);
        ((ushort*)((char*)Ps + pr * 128 + slot * 16))[fl & 7] = pv;
      }
    }

    const int prow = w * 16 + fl;
#pragma unroll
    for (int ks = 0; ks < 2; ++ks) {
      int slotA = (ks * 4 + fh) ^ (prow & 7);
      short8 pa = *(const short8*)((char*)Ps + prow * 128 + slotA * 16);
#pragma unroll
      for (int n = 0; n < 8; ++n) {
        int vrow = n * 16 + fl;
        int slotB = (ks * 4 + fh) ^ (vrow & 7);
        short8 vb = *(const short8*)((char*)Vs + vrow * 128 + slotB * 16);
        oacc[n] = __builtin_amdgcn_mfma_f32_16x16x32_bf16(pa, vb, oacc[n], 0, 0, 0);
      }
    }
    __syncthreads();
  }

#pragma unroll
  for (int n = 0; n < 8; ++n) {
    const int c = h * DD + n * 16 + fl;
    const float al = oalpha[c], be = obeta[c];
#pragma unroll
    for (int j = 0; j < 4; ++j) {
      const int tq = q0 + w * 16 + fh * 4 + j;
      float v = oacc[n][j];
      hy[(size_t)tq * CC + c] = (v - be > 0.f) ? f2b(al) : (ushort)0;
    }
  }
}

// ---------- rope + hv on q/k, transpose+cast v ; fused split-K-2 sum ----------
__global__ __launch_bounds__(256)
void rope_hv_kernel(const float* __restrict__ qp0, const float* __restrict__ qp1,
                    const float* __restrict__ cs, const float* __restrict__ sn,
                    const float* __restrict__ qalpha, const float* __restrict__ qbeta,
                    const float* __restrict__ kalpha, const float* __restrict__ kbeta,
                    ushort* __restrict__ qb, ushort* __restrict__ kb,
                    ushort* __restrict__ vt)
{
  __shared__ ushort Vsh[64][129];
  const int t0 = blockIdx.x * 64, g = blockIdx.y;
  const int tid = threadIdx.x;
#pragma unroll
  for (int hh = 0; hh < 5; ++hh) {
    const float* alpha = (hh < 4) ? qalpha : kalpha;
    const float* beta = (hh < 4) ? qbeta : kbeta;
    const int hoff = (hh < 4) ? hh * 128 : 512;
    for (int it = 0; it < 16; ++it) {
      int idx = it * 256 + tid;
      int tr = idx >> 6, dd = idx & 63;
      size_t base = (size_t)(t0 + tr) * 3072 + g * 768 + hoff;
      float x1 = qp0[base + dd] + qp1[base + dd];
      float x2 = qp0[base + 64 + dd] + qp1[base + 64 + dd];
      float c = cs[(size_t)(t0 + tr) * 64 + dd];
      float s = sn[(size_t)(t0 + tr) * 64 + dd];
      float o1 = x1 * c - x2 * s, o2 = x1 * s + x2 * c;
      ushort b1 = (o1 - beta[dd] > 0.f) ? f2b(alpha[dd]) : (ushort)0;
      ushort b2 = (o2 - beta[64 + dd] > 0.f) ? f2b(alpha[64 + dd]) : (ushort)0;
      if (hh < 4) {
        size_t o = ((size_t)(g * 4 + hh) * TT + t0 + tr) * DD;
        qb[o + dd] = b1;
        qb[o + 64 + dd] = b2;
      } else {
        size_t o = ((size_t)g * TT + t0 + tr) * DD;
        kb[o + dd] = b1;
        kb[o + 64 + dd] = b2;
      }
    }
  }
  for (int it = 0; it < 32; ++it) {
    int idx = it * 256 + tid;
    int tr = idx >> 7, d = idx & 127;
    size_t src = (size_t)(t0 + tr) * 3072 + g * 768 + 640 + d;
    Vsh[tr][d] = f2b(qp0[src] + qp1[src]);
  }
  __syncthreads();
  for (int it = 0; it < 32; ++it) {
    int idx = it * 256 + tid;
    int d = idx >> 6, tl = idx & 63;
    vt[((size_t)g * DD + d) * TT + t0 + tl] = Vsh[tl][d];
  }
}

// ---------------- elementwise ----------------
__global__ void hv_cast_kernel(const float* __restrict__ x, const float* __restrict__ alpha,
                               const float* __restrict__ beta, ushort* __restrict__ out,
                               int n4, int cols) {
  for (int i = blockIdx.x * blockDim.x + threadIdx.x; i < n4; i += gridDim.x * blockDim.x) {
    float4 v = ((const float4*)x)[i];
    int c = (i * 4) & (cols - 1);
    ushort4 r;
    r.x = (v.x - beta[c] > 0.f) ? f2b(alpha[c]) : (ushort)0;
    r.y = (v.y - beta[c + 1] > 0.f) ? f2b(alpha[c + 1]) : (ushort)0;
    r.z = (v.z - beta[c + 2] > 0.f) ? f2b(alpha[c + 2]) : (ushort)0;
    r.w = (v.w - beta[c + 3] > 0.f) ? f2b(alpha[c + 3]) : (ushort)0;
    ((ushort4*)out)[i] = r;
  }
}

__global__ void cast_kernel(const float* __restrict__ x, ushort* __restrict__ out, int n4) {
  for (int i = blockIdx.x * blockDim.x + threadIdx.x; i < n4; i += gridDim.x * blockDim.x) {
    float4 v = ((const float4*)x)[i];
    ushort4 r;
    r.x = f2b(v.x); r.y = f2b(v.y); r.z = f2b(v.z); r.w = f2b(v.w);
    ((ushort4*)out)[i] = r;
  }
}

__global__ void norm_cast_kernel(const float* __restrict__ W, const float* __restrict__ mu,
                                 const float* __restrict__ inv, ushort* __restrict__ out,
                                 int n4, int cols) {
  for (int i = blockIdx.x * blockDim.x + threadIdx.x; i < n4; i += gridDim.x * blockDim.x) {
    float4 v = ((const float4*)W)[i];
    int c = (i * 4) & (cols - 1);
    ushort4 r;
    r.x = f2b((v.x - mu[c]) * inv[c]);
    r.y = f2b((v.y - mu[c + 1]) * inv[c + 1]);
    r.z = f2b((v.z - mu[c + 2]) * inv[c + 2]);
    r.w = f2b((v.w - mu[c + 3]) * inv[c + 3]);
    ((ushort4*)out)[i] = r;
  }
}

// ---------------- column stats ----------------
__global__ void stats1_kernel(const float* __restrict__ W, float* __restrict__ ps,
                              float* __restrict__ ps2, int cols) {
  int j = blockIdx.x * 256 + threadIdx.x;
  int chunk = blockIdx.y;
  const float* p = W + (size_t)chunk * 256 * cols + j;
  float s = 0.f, s2 = 0.f;
  for (int i = 0; i < 256; ++i) { float v = p[(size_t)i * cols]; s += v; s2 += v * v; }
  ps[chunk * cols + j] = s;
  ps2[chunk * cols + j] = s2;
}

__global__ void stats2_kernel(const float* __restrict__ ps, const float* __restrict__ ps2,
                              float* __restrict__ mu, float* __restrict__ inv,
                              const float* __restrict__ scale, int cols) {
  int j = blockIdx.x * 256 + threadIdx.x;
  float s = 0.f, s2 = 0.f;
  for (int c = 0; c < 8; ++c) { s += ps[c * cols + j]; s2 += ps2[c * cols + j]; }
  float m = s * (1.f / 2048.f);
  float var = s2 - s * m;
  float nn = sqrtf(fmaxf(var, 0.f));
  nn = fmaxf(nn, 1e-12f);
  mu[j] = m;
  inv[j] = scale[0] / nn;
}

extern "C" void kernel_launch(void* const* d_in, const int* in_sizes, int n_in,
                              void* d_out, int out_size, void* d_ws, size_t ws_size,
                              hipStream_t stream) {
  const float* x          = (const float*)d_in[0];
  const float* cosT       = (const float*)d_in[1];
  const float* sinT       = (const float*)d_in[2];
  const float* attn_w     = (const float*)d_in[3];
  const float* proj_w     = (const float*)d_in[4];
  const float* proj_scale = (const float*)d_in[5];
  const float* fc_w       = (const float*)d_in[6];
  const float* mlp_proj_w = (const float*)d_in[7];
  const float* mlp_scale  = (const float*)d_in[8];
  const float* in_alpha   = (const float*)d_in[9];
  const float* in_beta    = (const float*)d_in[10];
  const float* q_alpha    = (const float*)d_in[11];
  const float* q_beta     = (const float*)d_in[12];
  const float* k_alpha    = (const float*)d_in[13];
  const float* k_beta     = (const float*)d_in[14];
  const float* out_alpha  = (const float*)d_in[15];
  const float* out_beta   = (const float*)d_in[16];
  const float* act1_alpha = (const float*)d_in[17];
  const float* act1_beta  = (const float*)d_in[18];
  const float* act2_alpha = (const float*)d_in[19];
  const float* act2_beta  = (const float*)d_in[20];

  char* cur = (char*)d_ws;
  auto alloc = [&](size_t b) { void* p = cur; cur += (b + 255) & ~(size_t)255; return p; };

  // --- early-dead cluster (dead after attn): contiguous 58.73MB ---
  ushort* attn_wb = (ushort*)alloc((size_t)3072 * 2048 * 2);
  ushort* h_in    = (ushort*)alloc((size_t)2048 * 2048 * 2);
  float*  qkv     = (float*)alloc((size_t)2048 * 3072 * 4);   // scratch (part of cluster)
  ushort* qbuf    = (ushort*)alloc((size_t)HQ * TT * DD * 2);
  ushort* kbuf    = (ushort*)alloc((size_t)GG * TT * DD * 2);
  ushort* vtbuf   = (ushort*)alloc((size_t)GG * DD * TT * 2);
  // --- mid-dead ---
  ushort* projn   = (ushort*)alloc((size_t)2048 * 2048 * 2);
  ushort* fc_wb   = (ushort*)alloc((size_t)8192 * 2048 * 2);
  // --- live-late ---
  ushort* mlpn    = (ushort*)alloc((size_t)2048 * 8192 * 2);
  ushort* h_y     = (ushort*)alloc((size_t)2048 * 2048 * 2);
  float*  x2      = (float*)alloc((size_t)2048 * 2048 * 4);
  ushort* h2      = (ushort*)alloc((size_t)2048 * 2048 * 2);
  ushort* h3      = (ushort*)alloc((size_t)2048 * 8192 * 2);
  float* pp_s  = (float*)alloc(8 * 2048 * 4);
  float* pp_s2 = (float*)alloc(8 * 2048 * 4);
  float* mp_s  = (float*)alloc(8 * 8192 * 4);
  float* mp_s2 = (float*)alloc(8 * 8192 * 4);
  float* p_mu  = (float*)alloc(2048 * 4);
  float* p_inv = (float*)alloc(2048 * 4);
  float* m_mu  = (float*)alloc(8192 * 4);
  float* m_inv = (float*)alloc(8192 * 4);
  (void)qkv;

  const size_t PLANE_QKV = (size_t)2048 * 3072;
  const size_t PLANE     = (size_t)2048 * 2048;

  // split-K part planes alias dead regions:
  float* qkv_parts  = (float*)x2;       // 2 planes over [x2,h2,h3]=58.7MB (written later)
  float* cluster    = (float*)attn_wb;  // 58.73MB early-dead
  float* mlp_parts  = (float*)attn_wb;  // 4 planes over [cluster,projn,fc_wb]=100.7MB

  // weight prep
  stats1_kernel<<<dim3(8, 8), 256, 0, stream>>>(proj_w, pp_s, pp_s2, 2048);
  stats1_kernel<<<dim3(32, 8), 256, 0, stream>>>(mlp_proj_w, mp_s, mp_s2, 8192);
  stats2_kernel<<<8, 256, 0, stream>>>(pp_s, pp_s2, p_mu, p_inv, proj_scale, 2048);
  stats2_kernel<<<32, 256, 0, stream>>>(mp_s, mp_s2, m_mu, m_inv, mlp_scale, 8192);
  norm_cast_kernel<<<2048, 256, 0, stream>>>(proj_w, p_mu, p_inv, projn, 2048 * 2048 / 4, 2048);
  norm_cast_kernel<<<2048, 256, 0, stream>>>(mlp_proj_w, m_mu, m_inv, mlpn, 2048 * 8192 / 4, 8192);
  cast_kernel<<<2048, 256, 0, stream>>>(attn_w, attn_wb, 3072 * 2048 / 4);
  cast_kernel<<<2048, 256, 0, stream>>>(fc_w, fc_wb, 8192 * 2048 / 4);

  // h = hv(x)
  hv_cast_kernel<<<2048, 256, 0, stream>>>(x, in_alpha, in_beta, h_in, 2048 * 2048 / 4, 2048);

  // qkv = h @ attn_w^T   (split-K x2; sum fused into rope)
  gemm8p<3><<<dim3(3072 / 256, 2048 / 256, 2), 512, 0, stream>>>(
      h_in, attn_wb, qkv_parts, nullptr, nullptr, nullptr, 2048, 3072, 2048, 1024);

  // rope + hv -> q,k ; transpose v  (reads & sums the two qkv part planes)
  rope_hv_kernel<<<dim3(TT / 64, GG), 256, 0, stream>>>(
      qkv_parts, qkv_parts + PLANE_QKV, cosT, sinT,
      q_alpha, q_beta, k_alpha, k_beta, qbuf, kbuf, vtbuf);

  // fused causal relu attention, hv epilogue -> h_y
  attn_kernel<<<dim3(TT / 64, HQ), 256, 0, stream>>>(qbuf, kbuf, vtbuf, h_y, out_alpha, out_beta);

  // x2 = x + h_y @ projn^T (split-K x3, kc=704 -> 11/11/10 K-tiles), fused h2 = hv(x2)
  gemm8p<3><<<dim3(2048 / 256, 2048 / 256, 3), 512, 0, stream>>>(
      h_y, projn, cluster, nullptr, nullptr, nullptr, 2048, 2048, 2048, 704);
  reduce_kernel<3, 1><<<2048, 256, 0, stream>>>(
      cluster, cluster + PLANE, cluster + 2 * PLANE, nullptr,
      x, x2, h2, act1_alpha, act1_beta, 2048 * 2048 / 4, 2048);

  // h3 = hv(h2 @ fc_w^T)   (256 blocks, 1/CU, no split)
  gemm8p<1><<<dim3(8192 / 256, 2048 / 256, 1), 512, 0, stream>>>(
      h2, fc_wb, nullptr, h3, act2_alpha, act2_beta, 2048, 8192, 2048, 2048);

  // out = x2 + h3 @ mlpn^T (split-K x4, kc=2048, 256 blocks)
  gemm8p<3><<<dim3(8, 8, 4), 512, 0, stream>>>(
      h3, mlpn, mlp_parts, nullptr, nullptr, nullptr, 2048, 2048, 8192, 2048);
  reduce_kernel<4, 2><<<2048, 256, 0, stream>>>(
      mlp_parts, mlp_parts + PLANE, mlp_parts + 2 * PLANE, mlp_parts + 3 * PLANE,
      x2, (float*)d_out, nullptr, nullptr, nullptr, 2048 * 2048 / 4, 1);
}

// Round 7
// 409.063 us; speedup vs baseline: 1.2287x; 1.0953x over previous
//
#include <hip/hip_runtime.h>

typedef __attribute__((ext_vector_type(8))) short short8;
typedef __attribute__((ext_vector_type(4))) float f32x4;

constexpr int TT = 2048, CC = 2048, HQ = 16, GG = 4, DD = 128, IC = 8192;

__device__ __forceinline__ ushort f2b(float f) {
  union { float f; unsigned u; } v; v.f = f;
  unsigned r = v.u + 0x7fffu + ((v.u >> 16) & 1u);
  return (ushort)(r >> 16);
}

__device__ __forceinline__ void gload16(const void* g, void* l) {
  __builtin_amdgcn_global_load_lds(
      (const __attribute__((address_space(1))) void*)g,
      (__attribute__((address_space(3))) void*)l, 16, 0, 0);
}

#define BAR()    __builtin_amdgcn_s_barrier()
#define PRIO1()  __builtin_amdgcn_s_setprio(1)
#define PRIO0()  __builtin_amdgcn_s_setprio(0)

// ============ 256x256 GEMM, relaxed 1-barrier pipeline (R6 structure, unchanged) ============
// EPI 1: Cb = hv(acc) bf16 ; EPI 3: f32 partial plane per blockIdx.z (plane 3 -> Cf3 if set)
template<int EPI>
__global__ __launch_bounds__(512, 2)
void gemm8p(const ushort* __restrict__ A, const ushort* __restrict__ B,
            float* __restrict__ Cf, float* __restrict__ Cf3, ushort* __restrict__ Cb,
            const float* __restrict__ alpha, const float* __restrict__ beta,
            int M, int N, int K, int kc)
{
  __shared__ alignas(16) char lds[131072];
  const int tid = threadIdx.x;
  const int l = tid & 63, w = tid >> 6;
  const int fl = l & 15, fh = l >> 4;
  const int wrm = w >> 2, wcn = w & 3;
  const int m0 = blockIdx.y * 256, n0 = blockIdx.x * 256;
  const int kBeg = blockIdx.z * kc;
  const int kEnd = (kBeg + kc < K) ? kBeg + kc : K;
  const int nt = (kEnd - kBeg) >> 6;

  f32x4 acc[8][4] = {};

  const int srow = tid >> 3;
  const int scol = ((tid & 7) ^ (srow & 7)) * 8;
  const ushort* Ag = A + (size_t)(m0 + srow) * K + kBeg + scol;
  const ushort* Bg = B + (size_t)(n0 + srow) * K + kBeg + scol;

  // h: 0 = Ah0 (rows 0-127), 1 = Ah1 (128-255), 2 = Bh0, 3 = Bh1
  auto stage_half = [&](int tile, int h) {
    const ushort* base = (h < 2) ? Ag : Bg;
    const int half = h & 1;
    const ushort* g = base + (size_t)(half * 128) * K + tile * 64;
    char* d = lds + (tile & 1) * 65536 + ((h < 2) ? 0 : 32768) + half * 16384 + tid * 16;
    gload16(g, d);
    gload16(g + (size_t)64 * K, d + 8192);
  };

  auto readA = [&](short8 (&dst)[4][2], int buf, int mofs) {
#pragma unroll
    for (int mf = 0; mf < 4; ++mf)
#pragma unroll
      for (int ks = 0; ks < 2; ++ks) {
        int row = wrm * 128 + (mofs + mf) * 16 + fl;
        dst[mf][ks] = *(const short8*)(lds + buf * 65536 + row * 128 +
                                       (((ks * 4 + fh) ^ (row & 7)) * 16));
      }
  };
  auto readB = [&](short8 (&dst)[2][2], int buf, int nofs) {
#pragma unroll
    for (int nf = 0; nf < 2; ++nf)
#pragma unroll
      for (int ks = 0; ks < 2; ++ks) {
        int row = wcn * 64 + (nofs + nf) * 16 + fl;
        dst[nf][ks] = *(const short8*)(lds + buf * 65536 + 32768 + row * 128 +
                                       (((ks * 4 + fh) ^ (row & 7)) * 16));
      }
  };
  auto mmQ = [&](short8 (&a)[4][2], short8 (&b)[2][2], int mo, int no) {
    PRIO1();
#pragma unroll
    for (int mf = 0; mf < 4; ++mf)
#pragma unroll
      for (int nf = 0; nf < 2; ++nf)
#pragma unroll
        for (int ks = 0; ks < 2; ++ks)
          acc[mo + mf][no + nf] = __builtin_amdgcn_mfma_f32_16x16x32_bf16(
              a[mf][ks], b[nf][ks], acc[mo + mf][no + nf], 0, 0, 0);
    PRIO0();
  };

  stage_half(0, 0); stage_half(0, 1); stage_half(0, 2); stage_half(0, 3);
  if (nt > 1) {
    stage_half(1, 2); stage_half(1, 3);
    asm volatile("s_waitcnt vmcnt(4)" ::: "memory");
  } else {
    asm volatile("s_waitcnt vmcnt(0)" ::: "memory");
  }
  BAR();

  for (int t = 0; t < nt; ++t) {
    const int buf = t & 1;
    short8 A0[4][2], A1[4][2], B0[2][2], B1[2][2];

    readA(A0, buf, 0);
    readB(B0, buf, 0);
    if (t + 1 < nt) stage_half(t + 1, 0);
    BAR();
    mmQ(A0, B0, 0, 0);

    readB(B1, buf, 2);
    if (t + 1 < nt) stage_half(t + 1, 1);
    BAR();
    mmQ(A0, B1, 0, 2);

    readA(A1, buf, 4);
    BAR();
    mmQ(A1, B0, 4, 0);

    if (t + 2 < nt) { stage_half(t + 2, 2); stage_half(t + 2, 3); }
    if (t <= nt - 3) asm volatile("s_waitcnt vmcnt(4)" ::: "memory");
    else             asm volatile("s_waitcnt vmcnt(0)" ::: "memory");
    BAR();
    mmQ(A1, B1, 4, 2);
  }

  const int orow0 = m0 + wrm * 128 + fh * 4;
  const int ocol0 = n0 + wcn * 64 + fl;
  float* Cpart = Cf;
  if constexpr (EPI == 3) {
    Cpart = (blockIdx.z == 3 && Cf3 != nullptr) ? Cf3 : Cf + (size_t)blockIdx.z * M * N;
  }
#pragma unroll
  for (int mf = 0; mf < 8; ++mf) {
#pragma unroll
    for (int nf = 0; nf < 4; ++nf) {
      const int c = ocol0 + nf * 16;
#pragma unroll
      for (int j = 0; j < 4; ++j) {
        const int r = orow0 + mf * 16 + j;
        const size_t o = (size_t)r * N + c;
        float v = acc[mf][nf][j];
        if constexpr (EPI == 1) {
          Cb[o] = (v - beta[c] > 0.f) ? f2b(alpha[c]) : (ushort)0;
        } else {
          Cpart[o] = v;
        }
      }
    }
  }
}

// ---------------- split-K reduce (per-plane pointers) ----------------
// MODE 1: outf = resid+sum, outb = hv(outf) ; MODE 2: outf = resid+sum
template<int NS, int MODE>
__global__ void reduce_kernel(const float* p0, const float* p1, const float* p2, const float* p3,
                              const float* resid, float* outf, ushort* outb,
                              const float* alpha, const float* beta, int n4, int cols)
{
  const float* ps[4] = {p0, p1, p2, p3};
  for (int i = blockIdx.x * blockDim.x + threadIdx.x; i < n4; i += gridDim.x * blockDim.x) {
    float4 s = ((const float4*)ps[0])[i];
#pragma unroll
    for (int z = 1; z < NS; ++z) {
      float4 p = ((const float4*)ps[z])[i];
      s.x += p.x; s.y += p.y; s.z += p.z; s.w += p.w;
    }
    float4 rr = ((const float4*)resid)[i];
    s.x += rr.x; s.y += rr.y; s.z += rr.z; s.w += rr.w;
    ((float4*)outf)[i] = s;
    if constexpr (MODE == 1) {
      int c = (i * 4) & (cols - 1);
      ushort4 r;
      r.x = (s.x - beta[c] > 0.f) ? f2b(alpha[c]) : (ushort)0;
      r.y = (s.y - beta[c + 1] > 0.f) ? f2b(alpha[c + 1]) : (ushort)0;
      r.z = (s.z - beta[c + 2] > 0.f) ? f2b(alpha[c + 2]) : (ushort)0;
      r.w = (s.w - beta[c + 3] > 0.f) ? f2b(alpha[c + 3]) : (ushort)0;
      ((ushort4*)outb)[i] = r;
    }
  }
}

// ---------------- fused causal relu-attention ----------------
// qi remap: blocks (bx,h) and (bx,h^8) get COMPLEMENTARY q-tiles (qi and 31-qi),
// so any CU that runs both does exactly 33 s-iterations total (load balance).
__global__ __launch_bounds__(256)
void attn_kernel(const ushort* __restrict__ qb, const ushort* __restrict__ kb,
                 const ushort* __restrict__ vt, ushort* __restrict__ hy,
                 const float* __restrict__ oalpha, const float* __restrict__ obeta)
{
  __shared__ alignas(16) ushort Qs[64 * 128];
  __shared__ alignas(16) ushort Ks[64 * 128];
  __shared__ alignas(16) ushort Vs[128 * 64];
  __shared__ alignas(16) ushort Ps[64 * 64];
  const int bx = blockIdx.x;
  const int h = blockIdx.y;
  const int qi = (h & 8) ? bx : (31 - bx);
  const int g = h >> 2;
  const int q0 = qi * 64;
  const int tid = threadIdx.x;
  const int w = tid >> 6, l = tid & 63;
  const int fl = l & 15, fh = l >> 4;

#pragma unroll
  for (int i = 0; i < 4; ++i) {
    int row = w * 16 + i * 4 + (l >> 4);
    int c16 = (l & 15) ^ (row & 7);
    gload16(qb + (size_t)h * TT * DD + (size_t)(q0 + row) * DD + c16 * 8,
            (char*)Qs + (w << 12) + (i << 10) + (l << 4));
  }

  f32x4 oacc[8] = {};

  for (int s0 = 0; s0 <= q0; s0 += 64) {
#pragma unroll
    for (int i = 0; i < 4; ++i) {
      int row = w * 16 + i * 4 + (l >> 4);
      int c16 = (l & 15) ^ (row & 7);
      gload16(kb + (size_t)g * TT * DD + (size_t)(s0 + row) * DD + c16 * 8,
              (char*)Ks + (w << 12) + (i << 10) + (l << 4));
    }
#pragma unroll
    for (int i = 0; i < 4; ++i) {
      int d = w * 32 + i * 8 + (l >> 3);
      int c16 = (l & 7) ^ (d & 7);
      gload16(vt + (size_t)g * DD * TT + (size_t)d * TT + s0 + c16 * 8,
              (char*)Vs + (w << 12) + (i << 10) + (l << 4));
    }
    __syncthreads();

    f32x4 sacc[4] = {};
    const int qrow = w * 16 + fl;
#pragma unroll
    for (int ks = 0; ks < 4; ++ks) {
      int slotA = (ks * 4 + fh) ^ (qrow & 7);
      short8 a = *(const short8*)((char*)Qs + qrow * 256 + slotA * 16);
#pragma unroll
      for (int n = 0; n < 4; ++n) {
        int krow = n * 16 + fl;
        int slotB = (ks * 4 + fh) ^ (krow & 7);
        short8 b = *(const short8*)((char*)Ks + krow * 256 + slotB * 16);
        sacc[n] = __builtin_amdgcn_mfma_f32_16x16x32_bf16(a, b, sacc[n], 0, 0, 0);
      }
    }

#pragma unroll
    for (int n = 0; n < 4; ++n) {
      const int scol = s0 + n * 16 + fl;
#pragma unroll
      for (int j = 0; j < 4; ++j) {
        const int pr = w * 16 + fh * 4 + j;
        const int qr = q0 + pr;
        float v = sacc[n][j] * 0.0078125f;
        ushort pv = (scol <= qr && v > 0.f) ? f2b(v) : (ushort)0;
        int slot = ((n * 2) + (fl >> 3)) ^ (pr & 7);
        ((ushort*)((char*)Ps + pr * 128 + slot * 16))[fl & 7] = pv;
      }
    }

    const int prow = w * 16 + fl;
#pragma unroll
    for (int ks = 0; ks < 2; ++ks) {
      int slotA = (ks * 4 + fh) ^ (prow & 7);
      short8 pa = *(const short8*)((char*)Ps + prow * 128 + slotA * 16);
#pragma unroll
      for (int n = 0; n < 8; ++n) {
        int vrow = n * 16 + fl;
        int slotB = (ks * 4 + fh) ^ (vrow & 7);
        short8 vb = *(const short8*)((char*)Vs + vrow * 128 + slotB * 16);
        oacc[n] = __builtin_amdgcn_mfma_f32_16x16x32_bf16(pa, vb, oacc[n], 0, 0, 0);
      }
    }
    __syncthreads();
  }

#pragma unroll
  for (int n = 0; n < 8; ++n) {
    const int c = h * DD + n * 16 + fl;
    const float al = oalpha[c], be = obeta[c];
#pragma unroll
    for (int j = 0; j < 4; ++j) {
      const int tq = q0 + w * 16 + fh * 4 + j;
      float v = oacc[n][j];
      hy[(size_t)tq * CC + c] = (v - be > 0.f) ? f2b(al) : (ushort)0;
    }
  }
}

// ---------- rope + hv on q/k, transpose+cast v ; fused split-K-2 sum ----------
__global__ __launch_bounds__(256)
void rope_hv_kernel(const float* __restrict__ qp0, const float* __restrict__ qp1,
                    const float* __restrict__ cs, const float* __restrict__ sn,
                    const float* __restrict__ qalpha, const float* __restrict__ qbeta,
                    const float* __restrict__ kalpha, const float* __restrict__ kbeta,
                    ushort* __restrict__ qb, ushort* __restrict__ kb,
                    ushort* __restrict__ vt)
{
  __shared__ ushort Vsh[64][129];
  const int t0 = blockIdx.x * 64, g = blockIdx.y;
  const int tid = threadIdx.x;
#pragma unroll
  for (int hh = 0; hh < 5; ++hh) {
    const float* alpha = (hh < 4) ? qalpha : kalpha;
    const float* beta = (hh < 4) ? qbeta : kbeta;
    const int hoff = (hh < 4) ? hh * 128 : 512;
    for (int it = 0; it < 16; ++it) {
      int idx = it * 256 + tid;
      int tr = idx >> 6, dd = idx & 63;
      size_t base = (size_t)(t0 + tr) * 3072 + g * 768 + hoff;
      float x1 = qp0[base + dd] + qp1[base + dd];
      float x2 = qp0[base + 64 + dd] + qp1[base + 64 + dd];
      float c = cs[(size_t)(t0 + tr) * 64 + dd];
      float s = sn[(size_t)(t0 + tr) * 64 + dd];
      float o1 = x1 * c - x2 * s, o2 = x1 * s + x2 * c;
      ushort b1 = (o1 - beta[dd] > 0.f) ? f2b(alpha[dd]) : (ushort)0;
      ushort b2 = (o2 - beta[64 + dd] > 0.f) ? f2b(alpha[64 + dd]) : (ushort)0;
      if (hh < 4) {
        size_t o = ((size_t)(g * 4 + hh) * TT + t0 + tr) * DD;
        qb[o + dd] = b1;
        qb[o + 64 + dd] = b2;
      } else {
        size_t o = ((size_t)g * TT + t0 + tr) * DD;
        kb[o + dd] = b1;
        kb[o + 64 + dd] = b2;
      }
    }
  }
  for (int it = 0; it < 32; ++it) {
    int idx = it * 256 + tid;
    int tr = idx >> 7, d = idx & 127;
    size_t src = (size_t)(t0 + tr) * 3072 + g * 768 + 640 + d;
    Vsh[tr][d] = f2b(qp0[src] + qp1[src]);
  }
  __syncthreads();
  for (int it = 0; it < 32; ++it) {
    int idx = it * 256 + tid;
    int d = idx >> 6, tl = idx & 63;
    vt[((size_t)g * DD + d) * TT + t0 + tl] = Vsh[tl][d];
  }
}

// ---------------- fused weight-prep megacast (5 jobs, 512 blocks each) ----------------
// job0: projn = bf16((proj_w - mu_p) * inv_p)        [1048576 f4, cols 2048]
// job1: mlpn  = bf16((mlp_w  - mu_m) * inv_m)        [4194304 f4, cols 8192]
// job2: attn_wb = bf16(attn_w)                        [1572864 f4]
// job3: fc_wb   = bf16(fc_w)                          [4194304 f4]
// job4: h_in    = hv(x, in_alpha, in_beta)            [1048576 f4, cols 2048]
__global__ void megacast_kernel(const float* __restrict__ proj_w, const float* __restrict__ mu_p,
                                const float* __restrict__ inv_p, ushort* __restrict__ projn,
                                const float* __restrict__ mlp_w, const float* __restrict__ mu_m,
                                const float* __restrict__ inv_m, ushort* __restrict__ mlpn,
                                const float* __restrict__ attn_w, ushort* __restrict__ attn_wb,
                                const float* __restrict__ fc_w, ushort* __restrict__ fc_wb,
                                const float* __restrict__ x, const float* __restrict__ ia,
                                const float* __restrict__ ib, ushort* __restrict__ h_in)
{
  const int job = blockIdx.x >> 9;
  const int blk = blockIdx.x & 511;
  const int stride = 512 * blockDim.x;
  int i0 = blk * blockDim.x + threadIdx.x;
  if (job == 0) {
    for (int i = i0; i < 1048576; i += stride) {
      float4 v = ((const float4*)proj_w)[i];
      int c = (i * 4) & 2047;
      ushort4 r;
      r.x = f2b((v.x - mu_p[c]) * inv_p[c]);
      r.y = f2b((v.y - mu_p[c + 1]) * inv_p[c + 1]);
      r.z = f2b((v.z - mu_p[c + 2]) * inv_p[c + 2]);
      r.w = f2b((v.w - mu_p[c + 3]) * inv_p[c + 3]);
      ((ushort4*)projn)[i] = r;
    }
  } else if (job == 1) {
    for (int i = i0; i < 4194304; i += stride) {
      float4 v = ((const float4*)mlp_w)[i];
      int c = (i * 4) & 8191;
      ushort4 r;
      r.x = f2b((v.x - mu_m[c]) * inv_m[c]);
      r.y = f2b((v.y - mu_m[c + 1]) * inv_m[c + 1]);
      r.z = f2b((v.z - mu_m[c + 2]) * inv_m[c + 2]);
      r.w = f2b((v.w - mu_m[c + 3]) * inv_m[c + 3]);
      ((ushort4*)mlpn)[i] = r;
    }
  } else if (job == 2) {
    for (int i = i0; i < 1572864; i += stride) {
      float4 v = ((const float4*)attn_w)[i];
      ushort4 r;
      r.x = f2b(v.x); r.y = f2b(v.y); r.z = f2b(v.z); r.w = f2b(v.w);
      ((ushort4*)attn_wb)[i] = r;
    }
  } else if (job == 3) {
    for (int i = i0; i < 4194304; i += stride) {
      float4 v = ((const float4*)fc_w)[i];
      ushort4 r;
      r.x = f2b(v.x); r.y = f2b(v.y); r.z = f2b(v.z); r.w = f2b(v.w);
      ((ushort4*)fc_wb)[i] = r;
    }
  } else {
    for (int i = i0; i < 1048576; i += stride) {
      float4 v = ((const float4*)x)[i];
      int c = (i * 4) & 2047;
      ushort4 r;
      r.x = (v.x - ib[c] > 0.f) ? f2b(ia[c]) : (ushort)0;
      r.y = (v.y - ib[c + 1] > 0.f) ? f2b(ia[c + 1]) : (ushort)0;
      r.z = (v.z - ib[c + 2] > 0.f) ? f2b(ia[c + 2]) : (ushort)0;
      r.w = (v.w - ib[c + 3] > 0.f) ? f2b(ia[c + 3]) : (ushort)0;
      ((ushort4*)h_in)[i] = r;
    }
  }
}

// ---------------- column stats (merged proj+mlp) ----------------
// grid (40, 8): bx<8 -> proj (cols 2048), else mlp (cols 8192)
__global__ void stats1_all(const float* __restrict__ pw, const float* __restrict__ mw,
                           float* __restrict__ ps, float* __restrict__ ps2,
                           float* __restrict__ ms, float* __restrict__ ms2)
{
  const int bx = blockIdx.x, chunk = blockIdx.y;
  const float* W;
  float* os; float* os2; int cols, j;
  if (bx < 8) { W = pw; os = ps; os2 = ps2; cols = 2048; j = bx * 256 + threadIdx.x; }
  else        { W = mw; os = ms; os2 = ms2; cols = 8192; j = (bx - 8) * 256 + threadIdx.x; }
  const float* p = W + (size_t)chunk * 256 * cols + j;
  float s = 0.f, s2 = 0.f;
  for (int i = 0; i < 256; ++i) { float v = p[(size_t)i * cols]; s += v; s2 += v * v; }
  os[chunk * cols + j] = s;
  os2[chunk * cols + j] = s2;
}

// grid 40: bx<8 -> proj, else mlp
__global__ void stats2_all(const float* __restrict__ ps, const float* __restrict__ ps2,
                           float* __restrict__ p_mu, float* __restrict__ p_inv,
                           const float* __restrict__ pscale,
                           const float* __restrict__ ms, const float* __restrict__ ms2,
                           float* __restrict__ m_mu, float* __restrict__ m_inv,
                           const float* __restrict__ mscale)
{
  const int bx = blockIdx.x;
  const float* S; const float* S2; float* mu; float* inv; const float* sc; int cols, j;
  if (bx < 8) { S = ps; S2 = ps2; mu = p_mu; inv = p_inv; sc = pscale; cols = 2048; j = bx * 256 + threadIdx.x; }
  else        { S = ms; S2 = ms2; mu = m_mu; inv = m_inv; sc = mscale; cols = 8192; j = (bx - 8) * 256 + threadIdx.x; }
  float s = 0.f, s2 = 0.f;
  for (int c = 0; c < 8; ++c) { s += S[c * cols + j]; s2 += S2[c * cols + j]; }
  float m = s * (1.f / 2048.f);
  float var = s2 - s * m;
  float nn = sqrtf(fmaxf(var, 0.f));
  nn = fmaxf(nn, 1e-12f);
  mu[j] = m;
  inv[j] = sc[0] / nn;
}

extern "C" void kernel_launch(void* const* d_in, const int* in_sizes, int n_in,
                              void* d_out, int out_size, void* d_ws, size_t ws_size,
                              hipStream_t stream) {
  const float* x          = (const float*)d_in[0];
  const float* cosT       = (const float*)d_in[1];
  const float* sinT       = (const float*)d_in[2];
  const float* attn_w     = (const float*)d_in[3];
  const float* proj_w     = (const float*)d_in[4];
  const float* proj_scale = (const float*)d_in[5];
  const float* fc_w       = (const float*)d_in[6];
  const float* mlp_proj_w = (const float*)d_in[7];
  const float* mlp_scale  = (const float*)d_in[8];
  const float* in_alpha   = (const float*)d_in[9];
  const float* in_beta    = (const float*)d_in[10];
  const float* q_alpha    = (const float*)d_in[11];
  const float* q_beta     = (const float*)d_in[12];
  const float* k_alpha    = (const float*)d_in[13];
  const float* k_beta     = (const float*)d_in[14];
  const float* out_alpha  = (const float*)d_in[15];
  const float* out_beta   = (const float*)d_in[16];
  const float* act1_alpha = (const float*)d_in[17];
  const float* act1_beta  = (const float*)d_in[18];
  const float* act2_alpha = (const float*)d_in[19];
  const float* act2_beta  = (const float*)d_in[20];

  char* cur = (char*)d_ws;
  auto alloc = [&](size_t b) { void* p = cur; cur += (b + 255) & ~(size_t)255; return p; };

  // --- early-dead cluster (dead after attn): contiguous 58.73MB ---
  ushort* attn_wb = (ushort*)alloc((size_t)3072 * 2048 * 2);
  ushort* h_in    = (ushort*)alloc((size_t)2048 * 2048 * 2);
  float*  qkv     = (float*)alloc((size_t)2048 * 3072 * 4);   // scratch (part of cluster)
  ushort* qbuf    = (ushort*)alloc((size_t)HQ * TT * DD * 2);
  ushort* kbuf    = (ushort*)alloc((size_t)GG * TT * DD * 2);
  ushort* vtbuf   = (ushort*)alloc((size_t)GG * DD * TT * 2);
  // --- mid-dead ---
  ushort* projn   = (ushort*)alloc((size_t)2048 * 2048 * 2);
  ushort* fc_wb   = (ushort*)alloc((size_t)8192 * 2048 * 2);
  // --- live-late ---
  ushort* mlpn    = (ushort*)alloc((size_t)2048 * 8192 * 2);
  ushort* h_y     = (ushort*)alloc((size_t)2048 * 2048 * 2);
  float*  x2      = (float*)alloc((size_t)2048 * 2048 * 4);
  ushort* h2      = (ushort*)alloc((size_t)2048 * 2048 * 2);
  ushort* h3      = (ushort*)alloc((size_t)2048 * 8192 * 2);
  float* pp_s  = (float*)alloc(8 * 2048 * 4);
  float* pp_s2 = (float*)alloc(8 * 2048 * 4);
  float* mp_s  = (float*)alloc(8 * 8192 * 4);
  float* mp_s2 = (float*)alloc(8 * 8192 * 4);
  float* p_mu  = (float*)alloc(2048 * 4);
  float* p_inv = (float*)alloc(2048 * 4);
  float* m_mu  = (float*)alloc(8192 * 4);
  float* m_inv = (float*)alloc(8192 * 4);
  (void)qkv;

  const size_t PLANE_QKV = (size_t)2048 * 3072;
  const size_t PLANE     = (size_t)2048 * 2048;

  // split-K part planes alias dead regions:
  float* qkv_parts  = (float*)x2;       // 2 planes over [x2,h2,h3]=58.7MB (written later)
  float* cluster    = (float*)attn_wb;  // 58.73MB early-dead: proj planes 0-2
  float* proj_p3    = (float*)h3;       // proj plane 3 in h3 (dead until fc GEMM)
  float* mlp_parts  = (float*)attn_wb;  // 4 planes over [cluster,projn,fc_wb]=100.7MB

  // weight prep: 3 dispatches
  stats1_all<<<dim3(40, 8), 256, 0, stream>>>(proj_w, mlp_proj_w, pp_s, pp_s2, mp_s, mp_s2);
  stats2_all<<<40, 256, 0, stream>>>(pp_s, pp_s2, p_mu, p_inv, proj_scale,
                                     mp_s, mp_s2, m_mu, m_inv, mlp_scale);
  megacast_kernel<<<2560, 256, 0, stream>>>(proj_w, p_mu, p_inv, projn,
                                            mlp_proj_w, m_mu, m_inv, mlpn,
                                            attn_w, attn_wb, fc_w, fc_wb,
                                            x, in_alpha, in_beta, h_in);

  // qkv = h @ attn_w^T   (split-K x2; sum fused into rope)
  gemm8p<3><<<dim3(3072 / 256, 2048 / 256, 2), 512, 0, stream>>>(
      h_in, attn_wb, qkv_parts, nullptr, nullptr, nullptr, nullptr, 2048, 3072, 2048, 1024);

  // rope + hv -> q,k ; transpose v  (reads & sums the two qkv part planes)
  rope_hv_kernel<<<dim3(TT / 64, GG), 256, 0, stream>>>(
      qkv_parts, qkv_parts + PLANE_QKV, cosT, sinT,
      q_alpha, q_beta, k_alpha, k_beta, qbuf, kbuf, vtbuf);

  // fused causal relu attention (balanced qi remap), hv epilogue -> h_y
  attn_kernel<<<dim3(TT / 64, HQ), 256, 0, stream>>>(qbuf, kbuf, vtbuf, h_y, out_alpha, out_beta);

  // x2 = x + h_y @ projn^T (split-K x4, kc=512, 256 blocks; plane3 -> h3), fused h2 = hv(x2)
  gemm8p<3><<<dim3(2048 / 256, 2048 / 256, 4), 512, 0, stream>>>(
      h_y, projn, cluster, proj_p3, nullptr, nullptr, nullptr, 2048, 2048, 2048, 512);
  reduce_kernel<4, 1><<<2048, 256, 0, stream>>>(
      cluster, cluster + PLANE, cluster + 2 * PLANE, proj_p3,
      x, x2, h2, act1_alpha, act1_beta, 2048 * 2048 / 4, 2048);

  // h3 = hv(h2 @ fc_w^T)   (256 blocks, 1/CU, no split)
  gemm8p<1><<<dim3(8192 / 256, 2048 / 256, 1), 512, 0, stream>>>(
      h2, fc_wb, nullptr, nullptr, h3, act2_alpha, act2_beta, 2048, 8192, 2048, 2048);

  // out = x2 + h3 @ mlpn^T (split-K x4, kc=2048, 256 blocks)
  gemm8p<3><<<dim3(8, 8, 4), 512, 0, stream>>>(
      h3, mlpn, mlp_parts, nullptr, nullptr, nullptr, nullptr, 2048, 2048, 8192, 2048);
  reduce_kernel<4, 2><<<2048, 256, 0, stream>>>(
      mlp_parts, mlp_parts + PLANE, mlp_parts + 2 * PLANE, mlp_parts + 3 * PLANE,
      x2, (float*)d_out, nullptr, nullptr, nullptr, 2048 * 2048 / 4, 1);
}